// Round 1
// baseline (11.026 us; speedup 1.0000x reference)
//
#include <hip/hip_runtime.h>

// Problem: out[0,n,b] = x_real[n ^ 2048, b]; out[1,n,b] = x_imag[n ^ 2048, b]
// (U = X ⊗ I_2048 — swap top/bottom halves of the 4096-row state, batch B=512)
//
// Pure memory-bound permuted copy. N=4096 rows × B=512 f32 per tensor.
// Row = 512 floats = 128 float4 — fully coalesced at float4 granularity.

#define N_ROWS 4096
#define B_COLS 512
#define VEC4_PER_TENSOR ((N_ROWS * B_COLS) / 4)   // 524288 float4
#define VEC4_PER_ROW (B_COLS / 4)                 // 128

__global__ __launch_bounds__(256) void swap_halves_kernel(
    const float4* __restrict__ xr,
    const float4* __restrict__ xi,
    float4* __restrict__ out)
{
    int i = blockIdx.x * blockDim.x + threadIdx.x;   // [0, 524288)
    int row = i >> 7;            // i / 128
    int col = i & 127;           // i % 128
    int src = ((row ^ 2048) << 7) | col;             // flip MSB of row index
    out[i] = xr[src];                                // real plane
    out[i + VEC4_PER_TENSOR] = xi[src];              // imag plane
}

extern "C" void kernel_launch(void* const* d_in, const int* in_sizes, int n_in,
                              void* d_out, int out_size, void* d_ws, size_t ws_size,
                              hipStream_t stream) {
    const float4* xr = (const float4*)d_in[0];
    const float4* xi = (const float4*)d_in[1];
    float4* out = (float4*)d_out;

    const int total = VEC4_PER_TENSOR;   // threads, one float4 pair each
    const int block = 256;
    const int grid = total / block;      // 2048 blocks
    swap_halves_kernel<<<grid, block, 0, stream>>>(xr, xi, out);
}